// Round 12
// baseline (229.221 us; speedup 1.0000x reference)
//
#include <hip/hip_runtime.h>
#include <math.h>

#define FINF __builtin_inff()

using short8  = __attribute__((ext_vector_type(8))) short;
using floatx4 = __attribute__((ext_vector_type(4))) float;
union U4 { uint4 u; short8 s; };

__device__ __forceinline__ float leaky(float x){ return x > 0.f ? x : 0.01f*x; }

// fp32 -> bf16 (RNE) and pack two into a u32
__device__ __forceinline__ unsigned int f2bf(float f){
  unsigned int x = __float_as_uint(f);
  x += 0x7FFFu + ((x >> 16) & 1u);
  return x >> 16;
}
__device__ __forceinline__ unsigned int pack2(float lo, float hi){
  return f2bf(lo) | (f2bf(hi) << 16);
}
__device__ __forceinline__ float bflo(unsigned int u){ return __uint_as_float(u << 16); }
__device__ __forceinline__ float bfhi(unsigned int u){ return __uint_as_float(u & 0xFFFF0000u); }

// ---- k_prep: weight repack (incl. algebraic folds) + ubias + counts8 init ----
__global__ __launch_bounds__(256) void k_prep(const float* __restrict__ fc1,
        const float* __restrict__ fc2, const float* __restrict__ W1,
        const float* __restrict__ W2, const float* __restrict__ b1,
        const float* __restrict__ a1s, const float* __restrict__ a1d,
        const float* __restrict__ a2s, const float* __restrict__ a2d,
        unsigned short* __restrict__ wp1, unsigned short* __restrict__ wp2,
        float* __restrict__ ubias, int* __restrict__ counts8, int N){
  int b = blockIdx.x, t = threadIdx.x;
  if (b < 224){
    int idx = b*256 + t;
    if (idx < 32768){
      int i  = idx & 7;
      int l  = (idx >> 3) & 63;
      int kk = (idx >> 9) & 3;
      int nt = idx >> 11;
      int n = nt*16 + (l & 15);
      int k = kk*32 + ((l >> 4) << 3) + i;
      wp1[idx] = (unsigned short)f2bf(fc1[(size_t)(n >> 5)*4096 + k*32 + (n & 31)]);
    } else if (idx < 34816){
      int j = idx - 32768;
      int i = j & 7, l = (j >> 3) & 63, kk = j >> 9;
      int k = kk*32 + ((l >> 4) << 3) + i;
      int c = l & 15, hh = c >> 1;
      const float* f = fc1 + (size_t)hh*4096 + (size_t)k*32;
      const float* av = (c & 1) ? (a1d + hh*32) : (a1s + hh*32);
      float s = 0.f;
      #pragma unroll
      for (int o = 0; o < 32; o++) s += f[o]*av[o];
      wp1[idx] = (unsigned short)f2bf(s);
    } else if (idx < 36864){
      int j = idx - 34816;
      int i = j & 7, l = (j >> 3) & 63, kk = j >> 9;
      int k = kk*32 + ((l >> 4) << 3) + i;
      int c = l & 15;
      float s = 0.f;
      if (c < 8){
        #pragma unroll
        for (int o = 0; o < 16; o++) s += W1[k*16 + o]*W2[o*8 + c];
      } else {
        #pragma unroll
        for (int o = 0; o < 16; o++) s += W1[k*16 + o]*W2[(16 + o)*8 + (c - 8)];
      }
      wp1[idx] = (unsigned short)f2bf(s);
    } else {
      int j = idx - 36864;
      if (j < 16384){
        int i  = j & 7, l = (j >> 3) & 63, kk = (j >> 9) & 7, nt = j >> 12;
        int n = nt*16 + (l & 15);
        int k = kk*32 + ((l >> 4) << 3) + i;
        wp2[j] = (unsigned short)f2bf(fc2[(size_t)k*64 + n]);
      } else {
        int q = j - 16384;
        int i = q & 7, l = (q >> 3) & 63, kk = q >> 9;
        int k = kk*32 + ((l >> 4) << 3) + i;
        int c = l & 15;
        float s = 0.f;
        if (c == 0){
          for (int o = 0; o < 64; o++) s += fc2[(size_t)k*64 + o]*a2s[o];
        } else if (c == 1){
          for (int o = 0; o < 64; o++) s += fc2[(size_t)k*64 + o]*a2d[o];
        }
        wp2[j] = (unsigned short)f2bf(s);
      }
    }
  } else if (b == 224){
    if (t < 16){
      float s = 0.f;
      if (t < 8){
        #pragma unroll
        for (int o = 0; o < 16; o++) s += b1[o]*W2[o*8 + t];
      } else {
        #pragma unroll
        for (int o = 0; o < 16; o++) s += b1[o]*W2[(16 + o)*8 + (t - 8)];
      }
      ubias[t] = s;
    }
  } else {
    int i = (b - 225)*256 + t;
    if (i < N*8) counts8[i] = 0;
  }
}

// z1 GEMM via MFMA bf16 + fused es1/ed1 + u_s/u_d epilogue columns.
__global__ __launch_bounds__(256) void k_z1m(const float* __restrict__ h,
        const unsigned short* __restrict__ wp1, const float* __restrict__ ubias,
        unsigned short* __restrict__ z1u, float* __restrict__ es1,
        float* __restrict__ ed1, float* __restrict__ u_s, float* __restrict__ u_d,
        int N){
  __shared__ uint4 lw[4096];   // 64KB: tiles 0..15
  int t = threadIdx.x;
  const uint4* wp4 = (const uint4*)wp1;
  #pragma unroll
  for (int i = 0; i < 16; i++) lw[t + i*256] = wp4[t + i*256];
  __syncthreads();
  int l = t & 63, wv = t >> 6;
  int n0 = blockIdx.x*64, m0 = wv*16;
  int rowA = min(n0 + m0 + (l & 15), N-1);
  const float* hr = h + (size_t)rowA*128 + ((l >> 4) << 3);
  U4 a[4];
  #pragma unroll
  for (int kk = 0; kk < 4; kk++){
    float4 f0 = *(const float4*)(hr + kk*32);
    float4 f1 = *(const float4*)(hr + kk*32 + 4);
    a[kk].u.x = pack2(f0.x, f0.y); a[kk].u.y = pack2(f0.z, f0.w);
    a[kk].u.z = pack2(f1.x, f1.y); a[kk].u.w = pack2(f1.z, f1.w);
  }
  int node0 = n0 + m0 + ((l >> 4) << 2);
  int c = l & 15;
  float ub = ubias[c];
  #pragma unroll
  for (int nt = 0; nt < 18; nt++){
    floatx4 acc;
    float b0 = (nt == 17) ? ub : 0.f;
    acc[0] = b0; acc[1] = b0; acc[2] = b0; acc[3] = b0;
    #pragma unroll
    for (int kk = 0; kk < 4; kk++){
      U4 bfr;
      bfr.u = (nt < 16) ? lw[(nt*4 + kk)*64 + l] : wp4[(nt*4 + kk)*64 + l];
      acc = __builtin_amdgcn_mfma_f32_16x16x32_bf16(a[kk].s, bfr.s, acc, 0, 0, 0);
    }
    if (nt < 16){
      int col = nt*16 + c;
      #pragma unroll
      for (int i2 = 0; i2 < 4; i2++){
        int node = node0 + i2;
        if (node < N) z1u[(size_t)node*256 + col] = (unsigned short)f2bf(acc[i2]);
      }
    } else if (nt == 16){
      int hh = c >> 1;
      #pragma unroll
      for (int i2 = 0; i2 < 4; i2++){
        int node = node0 + i2;
        if (node < N){
          if (c & 1) ed1[node*8 + hh] = acc[i2];
          else       es1[node*8 + hh] = acc[i2];
        }
      }
    } else {
      #pragma unroll
      for (int i2 = 0; i2 < 4; i2++){
        int node = node0 + i2;
        if (node < N){
          if (c < 8) u_s[(size_t)node*8 + c] = acc[i2];
          else       u_d[(size_t)node*8 + (c - 8)] = acc[i2];
        }
      }
    }
  }
}

// gate edge score; XCD-replicated dst histogram + per-edge rank; block (min,max)
__global__ __launch_bounds__(256) void k_gate_edge(const float* __restrict__ u_s,
        const float* __restrict__ u_d,
        const int* __restrict__ src, const int* __restrict__ dst,
        const float* __restrict__ b2, const float* __restrict__ W3,
        const float* __restrict__ b3,
        float* __restrict__ sbuf, int* __restrict__ counts8,
        int* __restrict__ rank, float2* __restrict__ pmm, int E, int N){
  __shared__ float lb2[8], lw3[8];
  __shared__ float lb3;
  __shared__ float rmin[4], rmax[4];
  int t = threadIdx.x;
  if (t < 8){ lb2[t] = b2[t]; lw3[t] = W3[t]; }
  if (t == 8) lb3 = b3[0];
  __syncthreads();
  int e = blockIdx.x*blockDim.x + t;
  float s = 0.f;
  bool valid = (e < E);
  if (valid){
    int a = src[e], b = dst[e];
    float4 us0 = ((const float4*)(u_s + (size_t)a*8))[0];
    float4 us1 = ((const float4*)(u_s + (size_t)a*8))[1];
    float4 ud0 = ((const float4*)(u_d + (size_t)b*8))[0];
    float4 ud1 = ((const float4*)(u_d + (size_t)b*8))[1];
    float tv[8] = { us0.x+ud0.x, us0.y+ud0.y, us0.z+ud0.z, us0.w+ud0.w,
                    us1.x+ud1.x, us1.y+ud1.y, us1.z+ud1.z, us1.w+ud1.w };
    s = lb3;
    #pragma unroll
    for (int j = 0; j < 8; j++) s += fmaxf(tv[j] + lb2[j], 0.f)*lw3[j];
    sbuf[e] = s;
    rank[e] = atomicAdd(&counts8[(size_t)(blockIdx.x & 7)*N + b], 1);
  }
  float vmin = valid ? s : FINF;
  float vmax = valid ? s : -FINF;
  #pragma unroll
  for (int o = 32; o > 0; o >>= 1){
    vmin = fminf(vmin, __shfl_xor(vmin, o));
    vmax = fmaxf(vmax, __shfl_xor(vmax, o));
  }
  if ((t & 63) == 0){ rmin[t >> 6] = vmin; rmax[t >> 6] = vmax; }
  __syncthreads();
  if (t == 0){
    float mn = fminf(fminf(rmin[0], rmin[1]), fminf(rmin[2], rmin[3]));
    float mx = fmaxf(fmaxf(rmax[0], rmax[1]), fmaxf(rmax[2], rmax[3]));
    pmm[blockIdx.x] = make_float2(mn, mx);
  }
}

// ---- device-wide exclusive scan over node totals (3 kernels) ----
__global__ __launch_bounds__(256) void k_scan1(const int* __restrict__ counts8,
        int* __restrict__ indptr, int* __restrict__ blockSums, int N){
  __shared__ int wsum[4];
  int t = threadIdx.x;
  int base = blockIdx.x*1024 + t*4;
  int c[4];
  #pragma unroll
  for (int i = 0; i < 4; i++) c[i] = 0;
  for (int r = 0; r < 8; r++){
    const int* cr = counts8 + (size_t)r*N;
    #pragma unroll
    for (int i = 0; i < 4; i++) if (base + i < N) c[i] += cr[base + i];
  }
  int s = c[0] + c[1] + c[2] + c[3];
  int lane = t & 63, wid = t >> 6;
  int inc = s;
  #pragma unroll
  for (int o = 1; o < 64; o <<= 1){
    int v = __shfl_up(inc, o);
    if (lane >= o) inc += v;
  }
  if (lane == 63) wsum[wid] = inc;
  __syncthreads();
  int woff = 0;
  #pragma unroll
  for (int i = 0; i < 4; i++) if (i < wid) woff += wsum[i];
  int run = woff + inc - s;
  #pragma unroll
  for (int i = 0; i < 4; i++){
    if (base + i < N) indptr[base + i] = run;
    run += c[i];
  }
  if (t == 255) blockSums[blockIdx.x] = woff + inc;
}

__global__ __launch_bounds__(64) void k_scan2(int* __restrict__ blockSums,
        int* __restrict__ indptr, int B, int N,
        const float2* __restrict__ pmm, int GB, float* __restrict__ minmax){
  int t = threadIdx.x;
  int carry = 0;
  for (int b0 = 0; b0 < B; b0 += 64){
    int idx = b0 + t;
    int v = (idx < B) ? blockSums[idx] : 0;
    int inc = v;
    #pragma unroll
    for (int o = 1; o < 64; o <<= 1){
      int u = __shfl_up(inc, o);
      if (t >= o) inc += u;
    }
    if (idx < B) blockSums[idx] = carry + inc - v;
    carry += __shfl(inc, 63);
  }
  if (t == 0) indptr[N] = carry;
  float mn = FINF, mx = -FINF;
  for (int i = t; i < GB; i += 64){
    float2 v = pmm[i];
    mn = fminf(mn, v.x);
    mx = fmaxf(mx, v.y);
  }
  #pragma unroll
  for (int o = 32; o > 0; o >>= 1){
    mn = fminf(mn, __shfl_xor(mn, o));
    mx = fmaxf(mx, __shfl_xor(mx, o));
  }
  if (t == 0){ minmax[0] = mn; minmax[1] = mx; }
}

// pass3: finalize indptr; per-(node,replica) scatter offsets
__global__ __launch_bounds__(256) void k_scan3(int* __restrict__ indptr,
        const int* __restrict__ blockSums, const int* __restrict__ counts8,
        int* __restrict__ repoff, int N){
  int i = blockIdx.x*blockDim.x + threadIdx.x;
  if (i >= N) return;
  int v = indptr[i] + blockSums[i >> 10];
  indptr[i] = v;
  int run = v;
  for (int r = 0; r < 8; r++){
    repoff[(size_t)r*N + i] = run;
    run += counts8[(size_t)r*N + i];
  }
}

// atomic-free CSR scatter (rank precomputed); fused gate-normalize
__global__ void k_scatter(const int* __restrict__ src, const int* __restrict__ dst,
                          const float* __restrict__ sbuf, const float* __restrict__ minmax,
                          const int* __restrict__ rank, const int* __restrict__ repoff,
                          float* __restrict__ gate_out, uint2* __restrict__ eg,
                          int E, int N){
  int e = blockIdx.x*blockDim.x + threadIdx.x;
  if (e >= E) return;
  float mn = minmax[0], mx = minmax[1];
  float g = (sbuf[e] - mn) / (mx - mn);
  gate_out[e] = g;
  int r = blockIdx.x & 7;   // must match k_gate_edge's blocking
  int pos = repoff[(size_t)r*N + dst[e]] + rank[e];
  uint2 v; v.x = (unsigned int)src[e]; v.y = __float_as_uint(g);
  eg[pos] = v;
}

// fused layer1 softmax+aggregation + in-block z2 GEMM.
// Block = 16 dst nodes: 4 waves x 4 nodes (gather phase, hA rows -> LDS bf16),
// then one 16-row MFMA GEMM computes z2 (4 tiles) + es2/ed2 fold (tile 4).
__global__ __launch_bounds__(256) void k_gather1z(const int* __restrict__ indptr,
        const uint2* __restrict__ eg, const float* __restrict__ es1,
        const float* __restrict__ ed1, const unsigned int* __restrict__ z1b,
        const unsigned short* __restrict__ wp2, unsigned short* __restrict__ z2u,
        float* __restrict__ es2, float* __restrict__ ed2, int N){
  __shared__ float lap[4][64][8];              // 8KB staging of per-edge weights
  __shared__ unsigned short lha[16*264];       // 16 rows x 528B stride = 8448B
  int t = threadIdx.x;
  int w = t >> 6, lane = t & 63;
  int hh = lane >> 3;
  int nb = blockIdx.x*16;
  for (int j = 0; j < 4; j++){
    int row = w*4 + j;
    int n = nb + row;
    uint2 orow = make_uint2(0u, 0u);
    if (n < N){
      float4 ev0 = *(const float4*)(ed1 + (size_t)n*8);
      float4 ev1 = *(const float4*)(ed1 + (size_t)n*8 + 4);
      int beg = indptr[n], end = indptr[n+1];
      float4 acc = make_float4(0.f,0.f,0.f,0.f);
      float den = 0.f;
      for (int c = beg; c < end; c += 64){
        int len = min(64, end - c);
        int sv = 0;
        if (lane < len){
          uint2 v = eg[c + lane];
          sv = (int)v.x;
          float g = __uint_as_float(v.y);
          float4 e0 = *(const float4*)(es1 + (size_t)sv*8);
          float4 e1 = *(const float4*)(es1 + (size_t)sv*8 + 4);
          float4 w0, w1;
          w0.x = __expf(leaky(e0.x + ev0.x)*g);
          w0.y = __expf(leaky(e0.y + ev0.y)*g);
          w0.z = __expf(leaky(e0.z + ev0.z)*g);
          w0.w = __expf(leaky(e0.w + ev0.w)*g);
          w1.x = __expf(leaky(e1.x + ev1.x)*g);
          w1.y = __expf(leaky(e1.y + ev1.y)*g);
          w1.z = __expf(leaky(e1.z + ev1.z)*g);
          w1.w = __expf(leaky(e1.w + ev1.w)*g);
          *(float4*)&lap[w][lane][0] = w0;
          *(float4*)&lap[w][lane][4] = w1;
        }
        __builtin_amdgcn_wave_barrier();
        for (int jj = 0; jj < len; jj++){
          int a = __shfl(sv, jj);
          float wgt = lap[w][jj][hh];
          uint2 zv = *(const uint2*)(z1b + (size_t)a*128 + lane*2);
          den += wgt;
          acc.x += wgt*bflo(zv.x); acc.y += wgt*bfhi(zv.x);
          acc.z += wgt*bflo(zv.y); acc.w += wgt*bfhi(zv.y);
        }
        __builtin_amdgcn_wave_barrier();
      }
      float iv = 1.f / fmaxf(den, 1e-12f);
      orow.x = pack2(leaky(acc.x*iv), leaky(acc.y*iv));
      orow.y = pack2(leaky(acc.z*iv), leaky(acc.w*iv));
    }
    *(uint2*)(lha + row*264 + lane*4) = orow;   // hA cols 4*lane..4*lane+3
  }
  __syncthreads();
  // ---- z2 GEMM phase: A = 16 LDS rows, B = wp2 (L2), 5 tiles over 4 waves ----
  const uint4* wp4 = (const uint4*)wp2;
  int arow = lane & 15, aoff = (lane >> 4)*8;
  U4 a[8];
  #pragma unroll
  for (int kk = 0; kk < 8; kk++)
    a[kk].u = *(const uint4*)(lha + arow*264 + kk*32 + aoff);
  int node0 = nb + ((lane >> 4) << 2);
  int c = lane & 15;
  for (int nt = w; nt < 5; nt += 4){
    floatx4 acc = {0.f, 0.f, 0.f, 0.f};
    #pragma unroll
    for (int kk = 0; kk < 8; kk++){
      U4 bfr; bfr.u = wp4[(nt*8 + kk)*64 + lane];
      acc = __builtin_amdgcn_mfma_f32_16x16x32_bf16(a[kk].s, bfr.s, acc, 0, 0, 0);
    }
    if (nt < 4){
      int col = nt*16 + c;
      #pragma unroll
      for (int i2 = 0; i2 < 4; i2++){
        int node = node0 + i2;
        if (node < N) z2u[(size_t)node*64 + col] = (unsigned short)f2bf(acc[i2]);
      }
    } else {
      #pragma unroll
      for (int i2 = 0; i2 < 4; i2++){
        int node = node0 + i2;
        if (node < N){
          if (c == 0) es2[node] = acc[i2];
          else if (c == 1) ed2[node] = acc[i2];
        }
      }
    }
  }
}

// fused layer2 softmax+aggregation+edge-predictor-projection
__global__ __launch_bounds__(256) void k_gather2f(const int* __restrict__ indptr,
        const uint2* __restrict__ eg, const float* __restrict__ es2,
        const float* __restrict__ ed2, const unsigned int* __restrict__ z2b,
        const float* __restrict__ Wp, float* __restrict__ ps, float* __restrict__ pd,
        int N){
  __shared__ float lwp[256];
  int t = threadIdx.x;
  lwp[t] = Wp[t];
  __syncthreads();
  int n = blockIdx.x*8 + (t >> 5);
  if (n >= N) return;
  int l = t & 31;
  int sb = t & 32;   // shfl base within the wave (half 0 or half 1)
  float ed = ed2[n];
  int beg = indptr[n], end = indptr[n+1];
  float a0 = 0.f, a1 = 0.f, den = 0.f;
  for (int c = beg; c < end; c += 32){
    int len = min(32, end - c);
    int sv = 0; float wr = 0.f;
    if (l < len){
      uint2 v = eg[c + l];
      sv = (int)v.x;
      wr = __expf(leaky(es2[sv] + ed) * __uint_as_float(v.y));
    }
    for (int jj = 0; jj < len; jj++){
      int a = __shfl(sv, sb + jj);
      float wgt = __shfl(wr, sb + jj);
      unsigned int u = z2b[(size_t)a*32 + l];
      den += wgt;
      a0 += wgt*bflo(u);
      a1 += wgt*bfhi(u);
    }
  }
  float iv = 1.f / fmaxf(den, 1e-12f);
  float h0 = a0*iv, h1 = a1*iv;   // hB cols 2l, 2l+1
  float s0 = h0*lwp[4*l+0] + h1*lwp[4*l+2];
  float s1 = h0*lwp[4*l+1] + h1*lwp[4*l+3];
  float d0 = h0*lwp[128+4*l+0] + h1*lwp[128+4*l+2];
  float d1 = h0*lwp[128+4*l+1] + h1*lwp[128+4*l+3];
  #pragma unroll
  for (int o = 1; o < 32; o <<= 1){
    s0 += __shfl_xor(s0, o); s1 += __shfl_xor(s1, o);
    d0 += __shfl_xor(d0, o); d1 += __shfl_xor(d1, o);
  }
  if (l == 0){
    ps[(size_t)n*2]   = s0; ps[(size_t)n*2+1] = s1;
    pd[(size_t)n*2]   = d0; pd[(size_t)n*2+1] = d1;
  }
}

__global__ void k_edgepred(const int* __restrict__ src, const int* __restrict__ dst,
                           const float* __restrict__ ps, const float* __restrict__ pd,
                           const float* __restrict__ bp, float* __restrict__ out, int E){
  int e = blockIdx.x*blockDim.x + threadIdx.x;
  if (e >= E) return;
  int a = src[e], b = dst[e];
  float2 vs = ((const float2*)ps)[a];
  float2 vd = ((const float2*)pd)[b];
  float2 o;
  o.x = vs.x + vd.x + bp[0];
  o.y = vs.y + vd.y + bp[1];
  ((float2*)out)[e] = o;
}

extern "C" void kernel_launch(void* const* d_in, const int* in_sizes, int n_in,
                              void* d_out, int out_size, void* d_ws, size_t ws_size,
                              hipStream_t stream) {
  const float* h   = (const float*)d_in[0];
  const int*   src = (const int*)d_in[1];
  const int*   dst = (const int*)d_in[2];
  const float* W1  = (const float*)d_in[3];
  const float* b1  = (const float*)d_in[4];
  const float* W2  = (const float*)d_in[5];
  const float* b2  = (const float*)d_in[6];
  const float* W3  = (const float*)d_in[7];
  const float* b3  = (const float*)d_in[8];
  const float* fc1 = (const float*)d_in[9];
  const float* a1s = (const float*)d_in[10];
  const float* a1d = (const float*)d_in[11];
  const float* fc2 = (const float*)d_in[12];
  const float* a2s = (const float*)d_in[13];
  const float* a2d = (const float*)d_in[14];
  const float* Wp  = (const float*)d_in[15];
  const float* bp  = (const float*)d_in[16];

  const int N = in_sizes[0] / 128;
  const int E = in_sizes[1];

  float* out_score = (float*)d_out;             // [E,2]
  float* gate      = out_score + (size_t)E*2;   // [E]

  char* w = (char*)d_ws;
  size_t off = 0;
  auto alloc = [&](size_t bytes) -> void* {
    off = (off + 255) & ~(size_t)255;
    void* p = w + off; off += bytes; return p;
  };
  float* u_s  = (float*)alloc((size_t)N*8*4);
  float* u_d  = (float*)alloc((size_t)N*8*4);
  unsigned short* z1u = (unsigned short*)alloc((size_t)N*256*2);  // bf16 [N,256]
  unsigned short* z2u = (unsigned short*)alloc((size_t)N*64*2);   // bf16 [N,64]
  float* es1  = (float*)alloc((size_t)N*8*4);
  float* ed1  = (float*)alloc((size_t)N*8*4);
  float* sbuf = (float*)alloc((size_t)E*4);
  float* es2  = (float*)alloc((size_t)N*4);
  float* ed2  = (float*)alloc((size_t)N*4);
  float* minmax = (float*)alloc(2*4);
  float* ubias  = (float*)alloc(16*4);
  int* counts8 = (int*)alloc((size_t)N*8*4);
  int* repoff  = (int*)alloc((size_t)N*8*4);
  int* rank    = (int*)alloc((size_t)E*4);
  int* indptr = (int*)alloc(((size_t)N+1)*4);
  int* blockSums = (int*)alloc(1024*4);
  const int GATE_B = (E + 255)/256;
  float2* pmm = (float2*)alloc((size_t)GATE_B*8);
  uint2* eg   = (uint2*)alloc((size_t)E*8);
  unsigned short* wp1 = (unsigned short*)alloc(36864*2);  // 18 tiles
  unsigned short* wp2 = (unsigned short*)alloc(20480*2);  // 5 tiles
  (void)ws_size; (void)n_in; (void)out_size;

  // reuse: u_s/u_d dead after gate_edge -> ps/pd
  float* ps  = u_s;
  float* pd  = u_d;

  const int SCAN_B = (N + 1023)/1024;
  const int INIT_B = (N*8 + 255)/256;

  k_prep<<<225 + INIT_B, 256, 0, stream>>>(fc1, fc2, W1, W2, b1, a1s, a1d,
                                           a2s, a2d, wp1, wp2, ubias, counts8, N);
  k_z1m<<<(N + 63)/64, 256, 0, stream>>>(h, wp1, ubias, z1u, es1, ed1, u_s, u_d, N);
  k_gate_edge<<<GATE_B, 256, 0, stream>>>(u_s, u_d, src, dst, b2, W3, b3,
                                          sbuf, counts8, rank, pmm, E, N);
  k_scan1<<<SCAN_B, 256, 0, stream>>>(counts8, indptr, blockSums, N);
  k_scan2<<<1, 64, 0, stream>>>(blockSums, indptr, SCAN_B, N, pmm, GATE_B, minmax);
  k_scan3<<<(N + 255)/256, 256, 0, stream>>>(indptr, blockSums, counts8, repoff, N);
  k_scatter<<<GATE_B, 256, 0, stream>>>(src, dst, sbuf, minmax, rank, repoff,
                                        gate, eg, E, N);
  k_gather1z<<<(N + 15)/16, 256, 0, stream>>>(indptr, eg, es1, ed1,
                                              (const unsigned int*)z1u,
                                              wp2, z2u, es2, ed2, N);
  k_gather2f<<<(N + 7)/8, 256, 0, stream>>>(indptr, eg, es2, ed2,
                                            (const unsigned int*)z2u,
                                            Wp, ps, pd, N);
  k_edgepred<<<(E + 255)/256, 256, 0, stream>>>(src, dst, ps, pd, bp, out_score, E);
}

// Round 14
// 226.910 us; speedup vs baseline: 1.0102x; 1.0102x over previous
//
#include <hip/hip_runtime.h>
#include <math.h>

#define FINF __builtin_inff()

using short8  = __attribute__((ext_vector_type(8))) short;
using floatx4 = __attribute__((ext_vector_type(4))) float;
union U4 { uint4 u; short8 s; };

__device__ __forceinline__ float leaky(float x){ return x > 0.f ? x : 0.01f*x; }

// fp32 -> bf16 (RNE) and pack two into a u32
__device__ __forceinline__ unsigned int f2bf(float f){
  unsigned int x = __float_as_uint(f);
  x += 0x7FFFu + ((x >> 16) & 1u);
  return x >> 16;
}
__device__ __forceinline__ unsigned int pack2(float lo, float hi){
  return f2bf(lo) | (f2bf(hi) << 16);
}
__device__ __forceinline__ float bflo(unsigned int u){ return __uint_as_float(u << 16); }
__device__ __forceinline__ float bfhi(unsigned int u){ return __uint_as_float(u & 0xFFFF0000u); }

// ---- k_prep: weight repack (incl. algebraic folds) + ubias + counts8 init ----
__global__ __launch_bounds__(256) void k_prep(const float* __restrict__ fc1,
        const float* __restrict__ fc2, const float* __restrict__ W1,
        const float* __restrict__ W2, const float* __restrict__ b1,
        const float* __restrict__ a1s, const float* __restrict__ a1d,
        const float* __restrict__ a2s, const float* __restrict__ a2d,
        unsigned short* __restrict__ wp1, unsigned short* __restrict__ wp2,
        float* __restrict__ ubias, int* __restrict__ counts8, int N){
  int b = blockIdx.x, t = threadIdx.x;
  if (b < 224){
    int idx = b*256 + t;
    if (idx < 32768){
      int i  = idx & 7;
      int l  = (idx >> 3) & 63;
      int kk = (idx >> 9) & 3;
      int nt = idx >> 11;
      int n = nt*16 + (l & 15);
      int k = kk*32 + ((l >> 4) << 3) + i;
      wp1[idx] = (unsigned short)f2bf(fc1[(size_t)(n >> 5)*4096 + k*32 + (n & 31)]);
    } else if (idx < 34816){
      int j = idx - 32768;
      int i = j & 7, l = (j >> 3) & 63, kk = j >> 9;
      int k = kk*32 + ((l >> 4) << 3) + i;
      int c = l & 15, hh = c >> 1;
      const float* f = fc1 + (size_t)hh*4096 + (size_t)k*32;
      const float* av = (c & 1) ? (a1d + hh*32) : (a1s + hh*32);
      float s = 0.f;
      #pragma unroll
      for (int o = 0; o < 32; o++) s += f[o]*av[o];
      wp1[idx] = (unsigned short)f2bf(s);
    } else if (idx < 36864){
      int j = idx - 34816;
      int i = j & 7, l = (j >> 3) & 63, kk = j >> 9;
      int k = kk*32 + ((l >> 4) << 3) + i;
      int c = l & 15;
      float s = 0.f;
      if (c < 8){
        #pragma unroll
        for (int o = 0; o < 16; o++) s += W1[k*16 + o]*W2[o*8 + c];
      } else {
        #pragma unroll
        for (int o = 0; o < 16; o++) s += W1[k*16 + o]*W2[(16 + o)*8 + (c - 8)];
      }
      wp1[idx] = (unsigned short)f2bf(s);
    } else {
      int j = idx - 36864;
      if (j < 16384){
        int i  = j & 7, l = (j >> 3) & 63, kk = (j >> 9) & 7, nt = j >> 12;
        int n = nt*16 + (l & 15);
        int k = kk*32 + ((l >> 4) << 3) + i;
        wp2[j] = (unsigned short)f2bf(fc2[(size_t)k*64 + n]);
      } else {
        int q = j - 16384;
        int i = q & 7, l = (q >> 3) & 63, kk = q >> 9;
        int k = kk*32 + ((l >> 4) << 3) + i;
        int c = l & 15;
        float s = 0.f;
        if (c == 0){
          for (int o = 0; o < 64; o++) s += fc2[(size_t)k*64 + o]*a2s[o];
        } else if (c == 1){
          for (int o = 0; o < 64; o++) s += fc2[(size_t)k*64 + o]*a2d[o];
        }
        wp2[j] = (unsigned short)f2bf(s);
      }
    }
  } else if (b == 224){
    if (t < 16){
      float s = 0.f;
      if (t < 8){
        #pragma unroll
        for (int o = 0; o < 16; o++) s += b1[o]*W2[o*8 + t];
      } else {
        #pragma unroll
        for (int o = 0; o < 16; o++) s += b1[o]*W2[(16 + o)*8 + (t - 8)];
      }
      ubias[t] = s;
    }
  } else {
    int i = (b - 225)*256 + t;
    if (i < N*8) counts8[i] = 0;
  }
}

// z1 GEMM via MFMA bf16 + fused es1/ed1 + u_s/u_d epilogue columns.
__global__ __launch_bounds__(256) void k_z1m(const float* __restrict__ h,
        const unsigned short* __restrict__ wp1, const float* __restrict__ ubias,
        unsigned short* __restrict__ z1u, float* __restrict__ es1,
        float* __restrict__ ed1, float* __restrict__ u_s, float* __restrict__ u_d,
        int N){
  __shared__ uint4 lw[4096];   // 64KB: tiles 0..15
  int t = threadIdx.x;
  const uint4* wp4 = (const uint4*)wp1;
  #pragma unroll
  for (int i = 0; i < 16; i++) lw[t + i*256] = wp4[t + i*256];
  __syncthreads();
  int l = t & 63, wv = t >> 6;
  int n0 = blockIdx.x*64, m0 = wv*16;
  int rowA = min(n0 + m0 + (l & 15), N-1);
  const float* hr = h + (size_t)rowA*128 + ((l >> 4) << 3);
  U4 a[4];
  #pragma unroll
  for (int kk = 0; kk < 4; kk++){
    float4 f0 = *(const float4*)(hr + kk*32);
    float4 f1 = *(const float4*)(hr + kk*32 + 4);
    a[kk].u.x = pack2(f0.x, f0.y); a[kk].u.y = pack2(f0.z, f0.w);
    a[kk].u.z = pack2(f1.x, f1.y); a[kk].u.w = pack2(f1.z, f1.w);
  }
  int node0 = n0 + m0 + ((l >> 4) << 2);
  int c = l & 15;
  float ub = ubias[c];
  #pragma unroll
  for (int nt = 0; nt < 18; nt++){
    floatx4 acc;
    float b0 = (nt == 17) ? ub : 0.f;
    acc[0] = b0; acc[1] = b0; acc[2] = b0; acc[3] = b0;
    #pragma unroll
    for (int kk = 0; kk < 4; kk++){
      U4 bfr;
      bfr.u = (nt < 16) ? lw[(nt*4 + kk)*64 + l] : wp4[(nt*4 + kk)*64 + l];
      acc = __builtin_amdgcn_mfma_f32_16x16x32_bf16(a[kk].s, bfr.s, acc, 0, 0, 0);
    }
    if (nt < 16){
      int col = nt*16 + c;
      #pragma unroll
      for (int i2 = 0; i2 < 4; i2++){
        int node = node0 + i2;
        if (node < N) z1u[(size_t)node*256 + col] = (unsigned short)f2bf(acc[i2]);
      }
    } else if (nt == 16){
      int hh = c >> 1;
      #pragma unroll
      for (int i2 = 0; i2 < 4; i2++){
        int node = node0 + i2;
        if (node < N){
          if (c & 1) ed1[node*8 + hh] = acc[i2];
          else       es1[node*8 + hh] = acc[i2];
        }
      }
    } else {
      #pragma unroll
      for (int i2 = 0; i2 < 4; i2++){
        int node = node0 + i2;
        if (node < N){
          if (c < 8) u_s[(size_t)node*8 + c] = acc[i2];
          else       u_d[(size_t)node*8 + (c - 8)] = acc[i2];
        }
      }
    }
  }
}

// gate edge score; XCD-replicated dst histogram + per-edge rank; block (min,max)
__global__ __launch_bounds__(256) void k_gate_edge(const float* __restrict__ u_s,
        const float* __restrict__ u_d,
        const int* __restrict__ src, const int* __restrict__ dst,
        const float* __restrict__ b2, const float* __restrict__ W3,
        const float* __restrict__ b3,
        float* __restrict__ sbuf, int* __restrict__ counts8,
        int* __restrict__ rank, float2* __restrict__ pmm, int E, int N){
  __shared__ float lb2[8], lw3[8];
  __shared__ float lb3;
  __shared__ float rmin[4], rmax[4];
  int t = threadIdx.x;
  if (t < 8){ lb2[t] = b2[t]; lw3[t] = W3[t]; }
  if (t == 8) lb3 = b3[0];
  __syncthreads();
  int e = blockIdx.x*blockDim.x + t;
  float s = 0.f;
  bool valid = (e < E);
  if (valid){
    int a = src[e], b = dst[e];
    float4 us0 = ((const float4*)(u_s + (size_t)a*8))[0];
    float4 us1 = ((const float4*)(u_s + (size_t)a*8))[1];
    float4 ud0 = ((const float4*)(u_d + (size_t)b*8))[0];
    float4 ud1 = ((const float4*)(u_d + (size_t)b*8))[1];
    float tv[8] = { us0.x+ud0.x, us0.y+ud0.y, us0.z+ud0.z, us0.w+ud0.w,
                    us1.x+ud1.x, us1.y+ud1.y, us1.z+ud1.z, us1.w+ud1.w };
    s = lb3;
    #pragma unroll
    for (int j = 0; j < 8; j++) s += fmaxf(tv[j] + lb2[j], 0.f)*lw3[j];
    sbuf[e] = s;
    rank[e] = atomicAdd(&counts8[(size_t)(blockIdx.x & 7)*N + b], 1);
  }
  float vmin = valid ? s : FINF;
  float vmax = valid ? s : -FINF;
  #pragma unroll
  for (int o = 32; o > 0; o >>= 1){
    vmin = fminf(vmin, __shfl_xor(vmin, o));
    vmax = fmaxf(vmax, __shfl_xor(vmax, o));
  }
  if ((t & 63) == 0){ rmin[t >> 6] = vmin; rmax[t >> 6] = vmax; }
  __syncthreads();
  if (t == 0){
    float mn = fminf(fminf(rmin[0], rmin[1]), fminf(rmin[2], rmin[3]));
    float mx = fmaxf(fmaxf(rmax[0], rmax[1]), fmaxf(rmax[2], rmax[3]));
    pmm[blockIdx.x] = make_float2(mn, mx);
  }
}

// ---- device-wide exclusive scan over node totals (3 kernels) ----
__global__ __launch_bounds__(256) void k_scan1(const int* __restrict__ counts8,
        int* __restrict__ indptr, int* __restrict__ blockSums, int N){
  __shared__ int wsum[4];
  int t = threadIdx.x;
  int base = blockIdx.x*1024 + t*4;
  int c[4];
  #pragma unroll
  for (int i = 0; i < 4; i++) c[i] = 0;
  for (int r = 0; r < 8; r++){
    const int* cr = counts8 + (size_t)r*N;
    #pragma unroll
    for (int i = 0; i < 4; i++) if (base + i < N) c[i] += cr[base + i];
  }
  int s = c[0] + c[1] + c[2] + c[3];
  int lane = t & 63, wid = t >> 6;
  int inc = s;
  #pragma unroll
  for (int o = 1; o < 64; o <<= 1){
    int v = __shfl_up(inc, o);
    if (lane >= o) inc += v;
  }
  if (lane == 63) wsum[wid] = inc;
  __syncthreads();
  int woff = 0;
  #pragma unroll
  for (int i = 0; i < 4; i++) if (i < wid) woff += wsum[i];
  int run = woff + inc - s;
  #pragma unroll
  for (int i = 0; i < 4; i++){
    if (base + i < N) indptr[base + i] = run;
    run += c[i];
  }
  if (t == 255) blockSums[blockIdx.x] = woff + inc;
}

__global__ __launch_bounds__(64) void k_scan2(int* __restrict__ blockSums,
        int* __restrict__ indptr, int B, int N,
        const float2* __restrict__ pmm, int GB, float* __restrict__ minmax){
  int t = threadIdx.x;
  int carry = 0;
  for (int b0 = 0; b0 < B; b0 += 64){
    int idx = b0 + t;
    int v = (idx < B) ? blockSums[idx] : 0;
    int inc = v;
    #pragma unroll
    for (int o = 1; o < 64; o <<= 1){
      int u = __shfl_up(inc, o);
      if (t >= o) inc += u;
    }
    if (idx < B) blockSums[idx] = carry + inc - v;
    carry += __shfl(inc, 63);
  }
  if (t == 0) indptr[N] = carry;
  float mn = FINF, mx = -FINF;
  for (int i = t; i < GB; i += 64){
    float2 v = pmm[i];
    mn = fminf(mn, v.x);
    mx = fmaxf(mx, v.y);
  }
  #pragma unroll
  for (int o = 32; o > 0; o >>= 1){
    mn = fminf(mn, __shfl_xor(mn, o));
    mx = fmaxf(mx, __shfl_xor(mx, o));
  }
  if (t == 0){ minmax[0] = mn; minmax[1] = mx; }
}

// pass3: finalize indptr; per-(node,replica) scatter offsets
__global__ __launch_bounds__(256) void k_scan3(int* __restrict__ indptr,
        const int* __restrict__ blockSums, const int* __restrict__ counts8,
        int* __restrict__ repoff, int N){
  int i = blockIdx.x*blockDim.x + threadIdx.x;
  if (i >= N) return;
  int v = indptr[i] + blockSums[i >> 10];
  indptr[i] = v;
  int run = v;
  for (int r = 0; r < 8; r++){
    repoff[(size_t)r*N + i] = run;
    run += counts8[(size_t)r*N + i];
  }
}

// atomic-free CSR scatter (rank precomputed); fused gate-normalize
__global__ void k_scatter(const int* __restrict__ src, const int* __restrict__ dst,
                          const float* __restrict__ sbuf, const float* __restrict__ minmax,
                          const int* __restrict__ rank, const int* __restrict__ repoff,
                          float* __restrict__ gate_out, uint2* __restrict__ eg,
                          int E, int N){
  int e = blockIdx.x*blockDim.x + threadIdx.x;
  if (e >= E) return;
  float mn = minmax[0], mx = minmax[1];
  float g = (sbuf[e] - mn) / (mx - mn);
  gate_out[e] = g;
  int r = blockIdx.x & 7;   // must match k_gate_edge's blocking
  int pos = repoff[(size_t)r*N + dst[e]] + rank[e];
  uint2 v; v.x = (unsigned int)src[e]; v.y = __float_as_uint(g);
  eg[pos] = v;
}

// fused layer1 softmax+aggregation: one wave per dst node; staging lane computes
// 8 head-weights inline; den accumulated online. Writes hA as bf16.
__global__ __launch_bounds__(256) void k_gather1f(const int* __restrict__ indptr,
        const uint2* __restrict__ eg, const float* __restrict__ es1,
        const float* __restrict__ ed1, const unsigned int* __restrict__ z1b,
        unsigned int* __restrict__ hAb, int N){
  __shared__ float lap[4][64][8];
  int t = threadIdx.x;
  int w = t >> 6, lane = t & 63;
  int n = blockIdx.x*4 + w;
  if (n >= N) return;
  int hh = lane >> 3;
  float4 ev0 = *(const float4*)(ed1 + (size_t)n*8);
  float4 ev1 = *(const float4*)(ed1 + (size_t)n*8 + 4);
  int beg = indptr[n], end = indptr[n+1];
  float4 acc = make_float4(0.f,0.f,0.f,0.f);
  float den = 0.f;
  for (int c = beg; c < end; c += 64){
    int len = min(64, end - c);
    int sv = 0;
    if (lane < len){
      uint2 v = eg[c + lane];
      sv = (int)v.x;
      float g = __uint_as_float(v.y);
      float4 e0 = *(const float4*)(es1 + (size_t)sv*8);
      float4 e1 = *(const float4*)(es1 + (size_t)sv*8 + 4);
      float4 w0, w1;
      w0.x = __expf(leaky(e0.x + ev0.x)*g);
      w0.y = __expf(leaky(e0.y + ev0.y)*g);
      w0.z = __expf(leaky(e0.z + ev0.z)*g);
      w0.w = __expf(leaky(e0.w + ev0.w)*g);
      w1.x = __expf(leaky(e1.x + ev1.x)*g);
      w1.y = __expf(leaky(e1.y + ev1.y)*g);
      w1.z = __expf(leaky(e1.z + ev1.z)*g);
      w1.w = __expf(leaky(e1.w + ev1.w)*g);
      *(float4*)&lap[w][lane][0] = w0;
      *(float4*)&lap[w][lane][4] = w1;
    }
    __builtin_amdgcn_wave_barrier();
    for (int jj = 0; jj < len; jj++){
      int a = __shfl(sv, jj);
      float wgt = lap[w][jj][hh];
      uint2 zv = *(const uint2*)(z1b + (size_t)a*128 + lane*2);
      den += wgt;
      acc.x += wgt*bflo(zv.x); acc.y += wgt*bfhi(zv.x);
      acc.z += wgt*bflo(zv.y); acc.w += wgt*bfhi(zv.y);
    }
    __builtin_amdgcn_wave_barrier();
  }
  float iv = 1.f / fmaxf(den, 1e-12f);
  uint2 o;
  o.x = pack2(leaky(acc.x*iv), leaky(acc.y*iv));
  o.y = pack2(leaky(acc.z*iv), leaky(acc.w*iv));
  *(uint2*)(hAb + (size_t)n*128 + lane*2) = o;
}

// z2 GEMM via MFMA bf16 + fused es2/ed2 epilogue columns. Tiles 0..3 LDS, 4 L2.
__global__ __launch_bounds__(256) void k_z2m(const unsigned short* __restrict__ hAu,
        const unsigned short* __restrict__ wp2, unsigned short* __restrict__ z2u,
        float* __restrict__ es2, float* __restrict__ ed2, int N){
  __shared__ uint4 lw[2048];   // 32KB: tiles 0..3
  int t = threadIdx.x;
  const uint4* wp4 = (const uint4*)wp2;
  #pragma unroll
  for (int i = 0; i < 8; i++) lw[t + i*256] = wp4[t + i*256];
  __syncthreads();
  int l = t & 63, wv = t >> 6;
  int n0 = blockIdx.x*64, m0 = wv*16;
  int rowA = min(n0 + m0 + (l & 15), N-1);
  const unsigned short* ar = hAu + (size_t)rowA*256 + ((l >> 4) << 3);
  U4 a[8];
  #pragma unroll
  for (int kk = 0; kk < 8; kk++)
    a[kk].u = *(const uint4*)(ar + kk*32);
  int node0 = n0 + m0 + ((l >> 4) << 2);
  int c = l & 15;
  #pragma unroll
  for (int nt = 0; nt < 5; nt++){
    floatx4 acc = {0.f, 0.f, 0.f, 0.f};
    #pragma unroll
    for (int kk = 0; kk < 8; kk++){
      U4 bfr;
      bfr.u = (nt < 4) ? lw[(nt*8 + kk)*64 + l] : wp4[(nt*8 + kk)*64 + l];
      acc = __builtin_amdgcn_mfma_f32_16x16x32_bf16(a[kk].s, bfr.s, acc, 0, 0, 0);
    }
    if (nt < 4){
      int col = nt*16 + c;
      #pragma unroll
      for (int i2 = 0; i2 < 4; i2++){
        int node = node0 + i2;
        if (node < N) z2u[(size_t)node*64 + col] = (unsigned short)f2bf(acc[i2]);
      }
    } else {
      #pragma unroll
      for (int i2 = 0; i2 < 4; i2++){
        int node = node0 + i2;
        if (node < N){
          if (c == 0) es2[node] = acc[i2];
          else if (c == 1) ed2[node] = acc[i2];
        }
      }
    }
  }
}

// fused layer2 softmax+aggregation+edge-predictor-projection
__global__ __launch_bounds__(256) void k_gather2f(const int* __restrict__ indptr,
        const uint2* __restrict__ eg, const float* __restrict__ es2,
        const float* __restrict__ ed2, const unsigned int* __restrict__ z2b,
        const float* __restrict__ Wp, float* __restrict__ ps, float* __restrict__ pd,
        int N){
  __shared__ float lwp[256];
  int t = threadIdx.x;
  lwp[t] = Wp[t];
  __syncthreads();
  int n = blockIdx.x*8 + (t >> 5);
  if (n >= N) return;
  int l = t & 31;
  int sb = t & 32;   // shfl base within the wave (half 0 or half 1)
  float ed = ed2[n];
  int beg = indptr[n], end = indptr[n+1];
  float a0 = 0.f, a1 = 0.f, den = 0.f;
  for (int c = beg; c < end; c += 32){
    int len = min(32, end - c);
    int sv = 0; float wr = 0.f;
    if (l < len){
      uint2 v = eg[c + l];
      sv = (int)v.x;
      wr = __expf(leaky(es2[sv] + ed) * __uint_as_float(v.y));
    }
    for (int jj = 0; jj < len; jj++){
      int a = __shfl(sv, sb + jj);
      float wgt = __shfl(wr, sb + jj);
      unsigned int u = z2b[(size_t)a*32 + l];
      den += wgt;
      a0 += wgt*bflo(u);
      a1 += wgt*bfhi(u);
    }
  }
  float iv = 1.f / fmaxf(den, 1e-12f);
  float h0 = a0*iv, h1 = a1*iv;   // hB cols 2l, 2l+1
  float s0 = h0*lwp[4*l+0] + h1*lwp[4*l+2];
  float s1 = h0*lwp[4*l+1] + h1*lwp[4*l+3];
  float d0 = h0*lwp[128+4*l+0] + h1*lwp[128+4*l+2];
  float d1 = h0*lwp[128+4*l+1] + h1*lwp[128+4*l+3];
  #pragma unroll
  for (int o = 1; o < 32; o <<= 1){
    s0 += __shfl_xor(s0, o); s1 += __shfl_xor(s1, o);
    d0 += __shfl_xor(d0, o); d1 += __shfl_xor(d1, o);
  }
  if (l == 0){
    ps[(size_t)n*2]   = s0; ps[(size_t)n*2+1] = s1;
    pd[(size_t)n*2]   = d0; pd[(size_t)n*2+1] = d1;
  }
}

__global__ void k_edgepred(const int* __restrict__ src, const int* __restrict__ dst,
                           const float* __restrict__ ps, const float* __restrict__ pd,
                           const float* __restrict__ bp, float* __restrict__ out, int E){
  int e = blockIdx.x*blockDim.x + threadIdx.x;
  if (e >= E) return;
  int a = src[e], b = dst[e];
  float2 vs = ((const float2*)ps)[a];
  float2 vd = ((const float2*)pd)[b];
  float2 o;
  o.x = vs.x + vd.x + bp[0];
  o.y = vs.y + vd.y + bp[1];
  ((float2*)out)[e] = o;
}

extern "C" void kernel_launch(void* const* d_in, const int* in_sizes, int n_in,
                              void* d_out, int out_size, void* d_ws, size_t ws_size,
                              hipStream_t stream) {
  const float* h   = (const float*)d_in[0];
  const int*   src = (const int*)d_in[1];
  const int*   dst = (const int*)d_in[2];
  const float* W1  = (const float*)d_in[3];
  const float* b1  = (const float*)d_in[4];
  const float* W2  = (const float*)d_in[5];
  const float* b2  = (const float*)d_in[6];
  const float* W3  = (const float*)d_in[7];
  const float* b3  = (const float*)d_in[8];
  const float* fc1 = (const float*)d_in[9];
  const float* a1s = (const float*)d_in[10];
  const float* a1d = (const float*)d_in[11];
  const float* fc2 = (const float*)d_in[12];
  const float* a2s = (const float*)d_in[13];
  const float* a2d = (const float*)d_in[14];
  const float* Wp  = (const float*)d_in[15];
  const float* bp  = (const float*)d_in[16];

  const int N = in_sizes[0] / 128;
  const int E = in_sizes[1];

  float* out_score = (float*)d_out;             // [E,2]
  float* gate      = out_score + (size_t)E*2;   // [E]

  char* w = (char*)d_ws;
  size_t off = 0;
  auto alloc = [&](size_t bytes) -> void* {
    off = (off + 255) & ~(size_t)255;
    void* p = w + off; off += bytes; return p;
  };
  float* u_s  = (float*)alloc((size_t)N*8*4);
  float* u_d  = (float*)alloc((size_t)N*8*4);
  unsigned short* z1u = (unsigned short*)alloc((size_t)N*256*2);  // bf16 [N,256]
  unsigned short* hAu = (unsigned short*)alloc((size_t)N*256*2);  // bf16 [N,256]
  float* es1  = (float*)alloc((size_t)N*8*4);
  float* ed1  = (float*)alloc((size_t)N*8*4);
  float* sbuf = (float*)alloc((size_t)E*4);
  float* es2  = (float*)alloc((size_t)N*4);
  float* ed2  = (float*)alloc((size_t)N*4);
  float* minmax = (float*)alloc(2*4);
  float* ubias  = (float*)alloc(16*4);
  int* counts8 = (int*)alloc((size_t)N*8*4);
  int* repoff  = (int*)alloc((size_t)N*8*4);
  int* rank    = (int*)alloc((size_t)E*4);
  int* indptr = (int*)alloc(((size_t)N+1)*4);
  int* blockSums = (int*)alloc(1024*4);
  const int GATE_B = (E + 255)/256;
  float2* pmm = (float2*)alloc((size_t)GATE_B*8);
  uint2* eg   = (uint2*)alloc((size_t)E*8);
  unsigned short* wp1 = (unsigned short*)alloc(36864*2);  // 18 tiles
  unsigned short* wp2 = (unsigned short*)alloc(20480*2);  // 5 tiles
  (void)ws_size; (void)n_in; (void)out_size;

  // reuse: z1u dead after gather1f -> z2u; u_s/u_d dead after gate_edge -> ps/pd
  unsigned short* z2u = z1u;
  float* ps  = u_s;
  float* pd  = u_d;

  const int SCAN_B = (N + 1023)/1024;
  const int INIT_B = (N*8 + 255)/256;

  k_prep<<<225 + INIT_B, 256, 0, stream>>>(fc1, fc2, W1, W2, b1, a1s, a1d,
                                           a2s, a2d, wp1, wp2, ubias, counts8, N);
  k_z1m<<<(N + 63)/64, 256, 0, stream>>>(h, wp1, ubias, z1u, es1, ed1, u_s, u_d, N);
  k_gate_edge<<<GATE_B, 256, 0, stream>>>(u_s, u_d, src, dst, b2, W3, b3,
                                          sbuf, counts8, rank, pmm, E, N);
  k_scan1<<<SCAN_B, 256, 0, stream>>>(counts8, indptr, blockSums, N);
  k_scan2<<<1, 64, 0, stream>>>(blockSums, indptr, SCAN_B, N, pmm, GATE_B, minmax);
  k_scan3<<<(N + 255)/256, 256, 0, stream>>>(indptr, blockSums, counts8, repoff, N);
  k_scatter<<<GATE_B, 256, 0, stream>>>(src, dst, sbuf, minmax, rank, repoff,
                                        gate, eg, E, N);
  k_gather1f<<<(N + 3)/4, 256, 0, stream>>>(indptr, eg, es1, ed1,
                                            (const unsigned int*)z1u,
                                            (unsigned int*)hAu, N);
  k_z2m<<<(N + 63)/64, 256, 0, stream>>>(hAu, wp2, z2u, es2, ed2, N);
  k_gather2f<<<(N + 7)/8, 256, 0, stream>>>(indptr, eg, es2, ed2,
                                            (const unsigned int*)z2u,
                                            Wp, ps, pd, N);
  k_edgepred<<<(E + 255)/256, 256, 0, stream>>>(src, dst, ps, pd, bp, out_score, E);
}